// Round 9
// baseline (267.575 us; speedup 1.0000x reference)
//
#include <hip/hip_runtime.h>

#define N_NODES 100000
#define N_EDGES 1600000
#define NWIN 1024
#define WN 98                           // nodes per window; 1024*98 >= N
#define WCAP 4096                       // max edges per window (mean 1562)
#define CB ((N_EDGES + 4095) / 4096)    // 391 count blocks
#define FB ((N_EDGES + 16383) / 16384)  // 98 fill blocks
#define NTILES ((N_NODES + 63) / 64)    // 1563 row tiles of 64

// ---------------------------------------------------------------------------
// Fused GEMM0+GEMM1, scalar-W form:
//   lane = row (64 rows/block), wave = 16-col slice (4 waves = 64 cols).
//   W addresses are wave-uniform (readfirstlane) -> s_load through the
//   scalar cache; SGPR operand folds straight into v_fmac_f32.
//   X/AGG rows read directly from global (L1/L2-resident 16KB tile).
//   Only LDS use: column-major sH[c*65+r] h-exchange (2-way banks, free).
//   phase 1a: acc += X_row   · Wr0_cols
//   phase 1b: acc += AGG_row · Wl0_cols
//   h = relu(acc + bl0*(deg>0)) -> sH -> phase 2: h1 = h@Wl1.T+bl1, hr1 = h@Wr1.T
// ---------------------------------------------------------------------------
__global__ __launch_bounds__(256) void gemm01_kernel(
    const float* __restrict__ X, const float* __restrict__ AGG,
    const float* __restrict__ Wr0, const float* __restrict__ Wl0,
    const float* __restrict__ bl0, const unsigned* __restrict__ deg,
    const float* __restrict__ Wl1, const float* __restrict__ bl1,
    const float* __restrict__ Wr1, float* __restrict__ H1,
    float* __restrict__ HR1) {
  __shared__ float sH[64 * 65];  // column-major: sH[c*65 + r]
  const int t = threadIdx.x;
  const int lane = t & 63;
  const int cw = __builtin_amdgcn_readfirstlane(t >> 6);  // wave id, uniform
  const int c0 = cw * 16;
  const int rbase = blockIdx.x * 64;
  const int row = rbase + lane;
  const bool valid = row < N_NODES;
  const int rowc = valid ? row : (N_NODES - 1);  // clamped for loads

  const float4* __restrict__ X4 = (const float4*)X;
  const float4* __restrict__ A4 = (const float4*)AGG;
  const float4* __restrict__ Wr04 = (const float4*)Wr0;
  const float4* __restrict__ Wl04 = (const float4*)Wl0;

  float acc[16];
#pragma unroll
  for (int i = 0; i < 16; ++i) acc[i] = 0.f;

  // ---- phase 1a: X_row · Wr0 (this wave's 16 cols) ----
#pragma unroll 4
  for (int kq = 0; kq < 16; ++kq) {
    const float4 xq = X4[(size_t)rowc * 16 + kq];
#pragma unroll
    for (int i = 0; i < 16; ++i) {
      const float4 w = Wr04[(c0 + i) * 16 + kq];  // uniform -> s_load
      acc[i] = fmaf(xq.x, w.x, acc[i]);
      acc[i] = fmaf(xq.y, w.y, acc[i]);
      acc[i] = fmaf(xq.z, w.z, acc[i]);
      acc[i] = fmaf(xq.w, w.w, acc[i]);
    }
  }
  // ---- phase 1b: AGG_row · Wl0 ----
#pragma unroll 4
  for (int kq = 0; kq < 16; ++kq) {
    const float4 xq = A4[(size_t)rowc * 16 + kq];
#pragma unroll
    for (int i = 0; i < 16; ++i) {
      const float4 w = Wl04[(c0 + i) * 16 + kq];
      acc[i] = fmaf(xq.x, w.x, acc[i]);
      acc[i] = fmaf(xq.y, w.y, acc[i]);
      acc[i] = fmaf(xq.z, w.z, acc[i]);
      acc[i] = fmaf(xq.w, w.w, acc[i]);
    }
  }

  // ---- epilogue 0: h = relu(acc + bl0*(deg>0)) -> sH (LDS only) ----
  const float gate = (deg[rowc] > 0) ? 1.0f : 0.0f;
#pragma unroll
  for (int i = 0; i < 16; ++i) {
    const float h = fmaxf(fmaf(bl0[c0 + i], gate, acc[i]), 0.0f);
    sH[(c0 + i) * 65 + lane] = h;
    acc[i] = 0.f;
  }
  __syncthreads();

  // ---- phase 2: h_row @ {Wl1|Wr1}.T ----
  // cw 0,1 -> Wl1 rows 0-31 (h1); cw 2,3 -> Wr1 rows 0-31 (hr1)
  const bool left = cw < 2;
  const int cb = (cw & 1) * 16;  // row base within selected W
  const float4* __restrict__ W2 =
      left ? (const float4*)Wl1 : (const float4*)Wr1;
#pragma unroll 4
  for (int kq = 0; kq < 16; ++kq) {
    float xk0 = sH[(4 * kq + 0) * 65 + lane];
    float xk1 = sH[(4 * kq + 1) * 65 + lane];
    float xk2 = sH[(4 * kq + 2) * 65 + lane];
    float xk3 = sH[(4 * kq + 3) * 65 + lane];
#pragma unroll
    for (int i = 0; i < 16; ++i) {
      const float4 w = W2[(cb + i) * 16 + kq];
      acc[i] = fmaf(xk0, w.x, acc[i]);
      acc[i] = fmaf(xk1, w.y, acc[i]);
      acc[i] = fmaf(xk2, w.z, acc[i]);
      acc[i] = fmaf(xk3, w.w, acc[i]);
    }
  }

  if (valid) {
#pragma unroll
    for (int i = 0; i < 16; ++i)
      if (left) acc[i] += bl1[cb + i];
    float4* __restrict__ O4 = left ? (float4*)H1 : (float4*)HR1;
#pragma unroll
    for (int j = 0; j < 4; ++j) {
      float4 v;
      v.x = acc[4 * j + 0];
      v.y = acc[4 * j + 1];
      v.z = acc[4 * j + 2];
      v.w = acc[4 * j + 3];
      O4[(size_t)row * 8 + (cb >> 2) + j] = v;
    }
  }
}

// ---------------------------------------------------------------------------
// Edge bucketing by dst window (1024 windows of 98 nodes).
// ---------------------------------------------------------------------------
__global__ __launch_bounds__(256) void bucket_count(const int* __restrict__ ei,
                                                    unsigned* __restrict__ bcnt) {
  __shared__ unsigned h[NWIN];
  const int t = threadIdx.x;
  for (int i = t; i < NWIN; i += 256) h[i] = 0;
  __syncthreads();
  const long long base = (long long)blockIdx.x * 4096;
#pragma unroll
  for (int i = 0; i < 16; ++i) {
    const long long e = base + i * 256 + t;
    if (e < N_EDGES) {
      const unsigned d = (unsigned)ei[N_EDGES + e];
      atomicAdd(&h[d / WN], 1u);
    }
  }
  __syncthreads();
  for (int i = t; i < NWIN; i += 256) {
    const unsigned c = h[i];
    if (c) atomicAdd(&bcnt[i], c);
  }
}

__global__ __launch_bounds__(1024) void bucket_scan(
    const unsigned* __restrict__ bcnt, unsigned* __restrict__ bbase,
    unsigned* __restrict__ bcursor) {
  __shared__ unsigned s[NWIN];
  const int t = threadIdx.x;
  const unsigned v = bcnt[t];
  s[t] = v;
  __syncthreads();
  for (int off = 1; off < NWIN; off <<= 1) {
    const unsigned u = (t >= off) ? s[t - off] : 0u;
    __syncthreads();
    s[t] += u;
    __syncthreads();
  }
  const unsigned ex = s[t] - v;
  bbase[t] = ex;
  bcursor[t] = ex;
  if (t == NWIN - 1) bbase[NWIN] = s[NWIN - 1];
}

// 16384 edges/block: LDS histogram -> bulk cursor reservation -> packed
// (dl<<24|src) writes in contiguous per-bucket chunks.
__global__ __launch_bounds__(256) void bucket_fill(const int* __restrict__ ei,
                                                   unsigned* __restrict__ bcursor,
                                                   unsigned* __restrict__ ebuf) {
  __shared__ unsigned lcnt[NWIN], gbase[NWIN];
  const int t = threadIdx.x;
  for (int i = t; i < NWIN; i += 256) lcnt[i] = 0;
  __syncthreads();
  const long long base = (long long)blockIdx.x * 16384;
#pragma unroll 4
  for (int i = 0; i < 64; ++i) {
    const long long e = base + i * 256 + t;
    if (e < N_EDGES) {
      const unsigned d = (unsigned)ei[N_EDGES + e];
      atomicAdd(&lcnt[d / WN], 1u);
    }
  }
  __syncthreads();
  for (int i = t; i < NWIN; i += 256) {
    const unsigned c = lcnt[i];
    gbase[i] = c ? atomicAdd(&bcursor[i], c) : 0u;
    lcnt[i] = 0;  // reused as local cursor
  }
  __syncthreads();
#pragma unroll 4
  for (int i = 0; i < 64; ++i) {
    const long long e = base + i * 256 + t;
    if (e < N_EDGES) {
      const unsigned s = (unsigned)ei[e];
      const unsigned d = (unsigned)ei[N_EDGES + e];
      const unsigned b = d / WN, dl = d - b * WN;
      const unsigned off = atomicAdd(&lcnt[b], 1u);
      ebuf[gbase[b] + off] = (dl << 24) | s;
    }
  }
}

// ---------------------------------------------------------------------------
// Per-window counting sort (in LDS, in-place in ebuf) -> CSR order.
// ---------------------------------------------------------------------------
__global__ __launch_bounds__(256) void win_sort(unsigned* __restrict__ ebuf,
                                                const unsigned* __restrict__ bbase,
                                                unsigned* __restrict__ rowptr,
                                                unsigned* __restrict__ deg) {
  __shared__ unsigned earr[WCAP];
  __shared__ unsigned sorted[WCAP];
  __shared__ unsigned hist[WN], pre[WN + 1], cur[WN];
  const int t = threadIdx.x, w = blockIdx.x;
  const int lo = w * WN;
  const unsigned beg = bbase[w], end = bbase[w + 1];
  const int n = (int)(end - beg);
  for (int i = t; i < WN; i += 256) hist[i] = 0;
  __syncthreads();
  for (int i = t; i < n; i += 256) {
    const unsigned p = ebuf[beg + i];
    earr[i] = p;
    atomicAdd(&hist[p >> 24], 1u);
  }
  __syncthreads();
  if (t == 0) {
    unsigned run = 0;
    for (int i = 0; i < WN; ++i) {
      pre[i] = run;
      run += hist[i];
    }
    pre[WN] = run;
  }
  __syncthreads();
  for (int dl = t; dl < WN; dl += 256) {
    const int node = lo + dl;
    if (node <= N_NODES) rowptr[node] = beg + pre[dl];
    if (node < N_NODES) deg[node] = hist[dl];
    cur[dl] = pre[dl];
  }
  __syncthreads();
  for (int i = t; i < n; i += 256) {
    const unsigned p = earr[i];
    const unsigned pos = atomicAdd(&cur[p >> 24], 1u);
    sorted[pos] = p;
  }
  __syncthreads();
  for (int i = t; i < n; i += 256) ebuf[beg + i] = sorted[i];
}

// ---------------------------------------------------------------------------
// Gather-aggregate (mean) + optional base add: one wave per dst node.
// Edge entries are packed (dl<<24|src) -> src = p & 0xFFFFFF.
// ---------------------------------------------------------------------------
template <int F, bool HAS_BASE>
__global__ __launch_bounds__(256) void gather_comb(
    const float* __restrict__ H, const unsigned* __restrict__ rowptr,
    const unsigned* __restrict__ csr, const float* __restrict__ base_row,
    float* __restrict__ outp) {
  constexpr int G = F / 4;
  constexpr int NG = 64 / G;
  const int node = (int)((blockIdx.x * 256 + threadIdx.x) >> 6);
  const int lane = threadIdx.x & 63;
  if (node >= N_NODES) return;
  const int g = lane / G, q = lane % G;
  const unsigned beg = rowptr[node], end = rowptr[node + 1];
  const float inv = (end > beg) ? 1.0f / (float)(end - beg) : 0.0f;
  const float4* __restrict__ H4 = (const float4*)H;

  float4 a0 = {0.f, 0.f, 0.f, 0.f}, a1 = {0.f, 0.f, 0.f, 0.f};
  unsigned e = beg + g;
  for (; e + NG < end; e += 2 * NG) {
    const unsigned s0 = csr[e] & 0xFFFFFFu, s1 = csr[e + NG] & 0xFFFFFFu;
    const float4 v0 = H4[(size_t)s0 * G + q];
    const float4 v1 = H4[(size_t)s1 * G + q];
    a0.x += v0.x; a0.y += v0.y; a0.z += v0.z; a0.w += v0.w;
    a1.x += v1.x; a1.y += v1.y; a1.z += v1.z; a1.w += v1.w;
  }
  if (e < end) {
    const float4 v = H4[(size_t)(csr[e] & 0xFFFFFFu) * G + q];
    a0.x += v.x; a0.y += v.y; a0.z += v.z; a0.w += v.w;
  }
  float sx = a0.x + a1.x, sy = a0.y + a1.y;
  float sz = a0.z + a1.z, sw = a0.w + a1.w;
#pragma unroll
  for (int m = G; m < 64; m <<= 1) {
    sx += __shfl_xor(sx, m, 64);
    sy += __shfl_xor(sy, m, 64);
    sz += __shfl_xor(sz, m, 64);
    sw += __shfl_xor(sw, m, 64);
  }
  if (g == 0) {
    float4 r;
    r.x = sx * inv; r.y = sy * inv; r.z = sz * inv; r.w = sw * inv;
    if (HAS_BASE) {
      const float4 b = ((const float4*)base_row)[(size_t)node * G + q];
      r.x += b.x; r.y += b.y; r.z += b.z; r.w += b.w;
    }
    ((float4*)outp)[(size_t)node * G + q] = r;
  }
}

extern "C" void kernel_launch(void* const* d_in, const int* in_sizes, int n_in,
                              void* d_out, int out_size, void* d_ws,
                              size_t ws_size, hipStream_t stream) {
  const float* x = (const float*)d_in[0];
  const int* ei = (const int*)d_in[1];
  const float* Wl0 = (const float*)d_in[2];
  const float* bl0 = (const float*)d_in[3];
  const float* Wr0 = (const float*)d_in[4];
  const float* Wl1 = (const float*)d_in[5];
  const float* bl1 = (const float*)d_in[6];
  const float* Wr1 = (const float*)d_in[7];
  float* out = (float*)d_out;

  const int N = N_NODES;

  // Workspace:
  //   aggx : N*64 f32
  //   bufB : h1 [N,32] + hr1 [N,32]
  //   deg[N], bcnt[1024], bbase[1025], bcursor[1024], rowptr[N+1], ebuf[E]
  float* aggx = (float*)d_ws;
  float* bufB = aggx + (size_t)N * 64;
  unsigned* deg = (unsigned*)(bufB + (size_t)N * 64);
  unsigned* bcnt = deg + N;
  unsigned* bbase = bcnt + NWIN;
  unsigned* bcursor = bbase + (NWIN + 1);
  unsigned* rowptr = bcursor + NWIN;
  unsigned* ebuf = rowptr + (N + 1);
  float* h1 = bufB;
  float* hr1 = bufB + (size_t)N * 32;

  hipMemsetAsync(bcnt, 0, NWIN * sizeof(unsigned), stream);

  const dim3 blk(256);

  // ---- edge bucketing + per-window counting sort -> CSR (both layers) ----
  bucket_count<<<CB, blk, 0, stream>>>(ei, bcnt);
  bucket_scan<<<1, NWIN, 0, stream>>>(bcnt, bbase, bcursor);
  bucket_fill<<<FB, blk, 0, stream>>>(ei, bcursor, ebuf);
  win_sort<<<NWIN, blk, 0, stream>>>(ebuf, bbase, rowptr, deg);

  // ---- layer-0 aggregation: aggx = mean(x[src]) ----
  gather_comb<64, false><<<(N * 64 + 255) / 256, blk, 0, stream>>>(
      x, rowptr, ebuf, nullptr, aggx);

  // ---- fused GEMMs (scalar-W): h in LDS; emits h1, hr1 ----
  gemm01_kernel<<<NTILES, blk, 0, stream>>>(x, aggx, Wr0, Wl0, bl0, deg, Wl1,
                                            bl1, Wr1, h1, hr1);

  // ---- layer-1 aggregation + combine: out = mean(h1[src]) + hr1 ----
  gather_comb<32, true><<<(N * 64 + 255) / 256, blk, 0, stream>>>(
      h1, rowptr, ebuf, hr1, out);
}

// Round 10
// 192.528 us; speedup vs baseline: 1.3898x; 1.3898x over previous
//
#include <hip/hip_runtime.h>

#define N_NODES 100000
#define N_EDGES 1600000
#define NWIN 1024
#define WN 98                           // nodes per window; 1024*98 >= N
#define WCAP 4096                       // max edges per window (mean 1562)
#define CB ((N_EDGES + 4095) / 4096)    // 391 count blocks
#define FB ((N_EDGES + 16383) / 16384)  // 98 fill blocks
#define NTILES ((N_NODES + 63) / 64)    // 1563 row tiles of 64

typedef __attribute__((ext_vector_type(8))) short bf16x8;
typedef __attribute__((ext_vector_type(4))) float f32x4;

__device__ __forceinline__ unsigned short f2bf(float f) {
  unsigned u = __builtin_bit_cast(unsigned, f);
  u += 0x7FFFu + ((u >> 16) & 1u);  // RNE
  return (unsigned short)(u >> 16);
}
__device__ __forceinline__ float bf2f(unsigned short s) {
  return __builtin_bit_cast(float, (unsigned)s << 16);
}

// ---------------------------------------------------------------------------
// Convert x and the four W matrices to bf16 (one pass).
// Wb layout (ushort): Wr0b @0 (4096), Wl0b @4096, Wl1b @8192, Wr1b @10240.
// ---------------------------------------------------------------------------
__global__ __launch_bounds__(256) void conv_bf16(
    const float4* __restrict__ X4, const float4* __restrict__ Wr0,
    const float4* __restrict__ Wl0, const float4* __restrict__ Wl1,
    const float4* __restrict__ Wr1, ushort4* __restrict__ Xb,
    ushort4* __restrict__ Wb) {
  const int i = blockIdx.x * 256 + threadIdx.x;
  float4 v;
  ushort4* dst;
  if (i < N_NODES * 16) {
    v = X4[i];
    dst = &Xb[i];
  } else {
    const int j = i - N_NODES * 16;
    if (j < 1024) v = Wr0[j];
    else if (j < 2048) v = Wl0[j - 1024];
    else if (j < 2560) v = Wl1[j - 2048];
    else if (j < 3072) v = Wr1[j - 2560];
    else return;
    dst = &Wb[j];
  }
  ushort4 o;
  o.x = f2bf(v.x); o.y = f2bf(v.y); o.z = f2bf(v.z); o.w = f2bf(v.w);
  *dst = o;
}

// ---------------------------------------------------------------------------
// Fused GEMM0+GEMM1 on matrix cores (mfma_f32_16x16x32_bf16).
// Block = 64 rows, 4 waves; wave w owns rows w*16..+16, all 64 cols (4 cn).
// A-frag: row = lane&15 (+16w), k = (lane>>4)*8+i  -> 16B direct loads.
// B-frag: col = lane&15 (+16cn), same k-mapping from W rows (bf16).
// (any per-lane k-permutation cancels between A and B.)
// C/D: col = lane&15, row = (lane>>4)*4 + reg   [verified m89/m91].
//   phase 1: acc = x.Wr0^T + aggx.Wl0^T ; h = relu(acc + bl0*(deg>0)) -> sH
//   phase 2: h1 = h.Wl1^T + bl1 (bf16 out), hr1 = h.Wr1^T (f32 out)
// ---------------------------------------------------------------------------
__global__ __launch_bounds__(256) void gemm01_mfma(
    const unsigned short* __restrict__ Xb,
    const unsigned short* __restrict__ AGGb,
    const unsigned short* __restrict__ Wb, const float* __restrict__ bl0,
    const unsigned* __restrict__ deg, const float* __restrict__ bl1,
    unsigned short* __restrict__ H1b, float* __restrict__ HR1) {
  __shared__ unsigned short sH[64 * 72];  // +8 bf16 pad: 2-way banks on read
  const int t = threadIdx.x;
  const int lane = t & 63;
  const int w = t >> 6;
  const int rbase = blockIdx.x * 64;
  const int lr = lane & 15;   // A row / B col / D col selector
  const int kg = lane >> 4;   // k-group
  const int row16 = w * 16 + lr;
  const int grow_a = rbase + row16;
  const size_t arow = (size_t)(grow_a < N_NODES ? grow_a : N_NODES - 1);

  const unsigned short* Wr0b = Wb;
  const unsigned short* Wl0b = Wb + 4096;
  const unsigned short* Wl1b = Wb + 8192;
  const unsigned short* Wr1b = Wb + 10240;

  f32x4 acc[4] = {{0, 0, 0, 0}, {0, 0, 0, 0}, {0, 0, 0, 0}, {0, 0, 0, 0}};

  // ---- phase 1: X.Wr0^T + AGG.Wl0^T ----
  {
    const bf16x8 ax0 = *(const bf16x8*)&Xb[arow * 64 + kg * 8];
    const bf16x8 ax1 = *(const bf16x8*)&Xb[arow * 64 + 32 + kg * 8];
    const bf16x8 ag0 = *(const bf16x8*)&AGGb[arow * 64 + kg * 8];
    const bf16x8 ag1 = *(const bf16x8*)&AGGb[arow * 64 + 32 + kg * 8];
#pragma unroll
    for (int cn = 0; cn < 4; ++cn) {
      const int wr = cn * 16 + lr;
      const bf16x8 br0 = *(const bf16x8*)&Wr0b[wr * 64 + kg * 8];
      const bf16x8 br1 = *(const bf16x8*)&Wr0b[wr * 64 + 32 + kg * 8];
      const bf16x8 bl0f = *(const bf16x8*)&Wl0b[wr * 64 + kg * 8];
      const bf16x8 bl1f = *(const bf16x8*)&Wl0b[wr * 64 + 32 + kg * 8];
      acc[cn] = __builtin_amdgcn_mfma_f32_16x16x32_bf16(ax0, br0, acc[cn], 0, 0, 0);
      acc[cn] = __builtin_amdgcn_mfma_f32_16x16x32_bf16(ax1, br1, acc[cn], 0, 0, 0);
      acc[cn] = __builtin_amdgcn_mfma_f32_16x16x32_bf16(ag0, bl0f, acc[cn], 0, 0, 0);
      acc[cn] = __builtin_amdgcn_mfma_f32_16x16x32_bf16(ag1, bl1f, acc[cn], 0, 0, 0);
    }
  }

  // ---- epilogue 0: h = relu(acc + bl0*(deg>0)) -> sH (bf16, LDS only) ----
  const int crow0 = w * 16 + (lane >> 4) * 4;
  float gate[4];
#pragma unroll
  for (int r = 0; r < 4; ++r) {
    const int grow = rbase + crow0 + r;
    gate[r] = (deg[grow < N_NODES ? grow : N_NODES - 1] > 0) ? 1.0f : 0.0f;
  }
#pragma unroll
  for (int cn = 0; cn < 4; ++cn) {
    const int col = cn * 16 + lr;
    const float bias = bl0[col];
#pragma unroll
    for (int r = 0; r < 4; ++r) {
      const float h = fmaxf(fmaf(bias, gate[r], acc[cn][r]), 0.0f);
      sH[(crow0 + r) * 72 + col] = f2bf(h);
    }
  }
  __syncthreads();

  // ---- phase 2: h.{Wl1|Wr1}^T ----
  f32x4 acc2[4] = {{0, 0, 0, 0}, {0, 0, 0, 0}, {0, 0, 0, 0}, {0, 0, 0, 0}};
  {
    const bf16x8 ah0 = *(const bf16x8*)&sH[row16 * 72 + kg * 8];
    const bf16x8 ah1 = *(const bf16x8*)&sH[row16 * 72 + 32 + kg * 8];
#pragma unroll
    for (int cn = 0; cn < 4; ++cn) {
      const int col = cn * 16 + lr;
      const unsigned short* Wp =
          (cn < 2) ? &Wl1b[col * 64] : &Wr1b[(col - 32) * 64];
      const bf16x8 b0 = *(const bf16x8*)&Wp[kg * 8];
      const bf16x8 b1 = *(const bf16x8*)&Wp[32 + kg * 8];
      acc2[cn] = __builtin_amdgcn_mfma_f32_16x16x32_bf16(ah0, b0, acc2[cn], 0, 0, 0);
      acc2[cn] = __builtin_amdgcn_mfma_f32_16x16x32_bf16(ah1, b1, acc2[cn], 0, 0, 0);
    }
  }

  // ---- epilogue 1: h1 (bf16, +bl1) and hr1 (f32) ----
#pragma unroll
  for (int cn = 0; cn < 4; ++cn) {
    const int col = cn * 16 + lr;
    const float bias = (cn < 2) ? bl1[col] : 0.0f;
#pragma unroll
    for (int r = 0; r < 4; ++r) {
      const int grow = rbase + crow0 + r;
      if (grow < N_NODES) {
        if (cn < 2)
          H1b[(size_t)grow * 32 + col] = f2bf(acc2[cn][r] + bias);
        else
          HR1[(size_t)grow * 32 + (col - 32)] = acc2[cn][r];
      }
    }
  }
}

// ---------------------------------------------------------------------------
// Edge bucketing by dst window (1024 windows of 98 nodes).
// ---------------------------------------------------------------------------
__global__ __launch_bounds__(256) void bucket_count(const int* __restrict__ ei,
                                                    unsigned* __restrict__ bcnt) {
  __shared__ unsigned h[NWIN];
  const int t = threadIdx.x;
  for (int i = t; i < NWIN; i += 256) h[i] = 0;
  __syncthreads();
  const long long base = (long long)blockIdx.x * 4096;
#pragma unroll
  for (int i = 0; i < 16; ++i) {
    const long long e = base + i * 256 + t;
    if (e < N_EDGES) {
      const unsigned d = (unsigned)ei[N_EDGES + e];
      atomicAdd(&h[d / WN], 1u);
    }
  }
  __syncthreads();
  for (int i = t; i < NWIN; i += 256) {
    const unsigned c = h[i];
    if (c) atomicAdd(&bcnt[i], c);
  }
}

__global__ __launch_bounds__(1024) void bucket_scan(
    const unsigned* __restrict__ bcnt, unsigned* __restrict__ bbase,
    unsigned* __restrict__ bcursor) {
  __shared__ unsigned s[NWIN];
  const int t = threadIdx.x;
  const unsigned v = bcnt[t];
  s[t] = v;
  __syncthreads();
  for (int off = 1; off < NWIN; off <<= 1) {
    const unsigned u = (t >= off) ? s[t - off] : 0u;
    __syncthreads();
    s[t] += u;
    __syncthreads();
  }
  const unsigned ex = s[t] - v;
  bbase[t] = ex;
  bcursor[t] = ex;
  if (t == NWIN - 1) bbase[NWIN] = s[NWIN - 1];
}

__global__ __launch_bounds__(256) void bucket_fill(const int* __restrict__ ei,
                                                   unsigned* __restrict__ bcursor,
                                                   unsigned* __restrict__ ebuf) {
  __shared__ unsigned lcnt[NWIN], gbase[NWIN];
  const int t = threadIdx.x;
  for (int i = t; i < NWIN; i += 256) lcnt[i] = 0;
  __syncthreads();
  const long long base = (long long)blockIdx.x * 16384;
#pragma unroll 4
  for (int i = 0; i < 64; ++i) {
    const long long e = base + i * 256 + t;
    if (e < N_EDGES) {
      const unsigned d = (unsigned)ei[N_EDGES + e];
      atomicAdd(&lcnt[d / WN], 1u);
    }
  }
  __syncthreads();
  for (int i = t; i < NWIN; i += 256) {
    const unsigned c = lcnt[i];
    gbase[i] = c ? atomicAdd(&bcursor[i], c) : 0u;
    lcnt[i] = 0;  // reused as local cursor
  }
  __syncthreads();
#pragma unroll 4
  for (int i = 0; i < 64; ++i) {
    const long long e = base + i * 256 + t;
    if (e < N_EDGES) {
      const unsigned s = (unsigned)ei[e];
      const unsigned d = (unsigned)ei[N_EDGES + e];
      const unsigned b = d / WN, dl = d - b * WN;
      const unsigned off = atomicAdd(&lcnt[b], 1u);
      ebuf[gbase[b] + off] = (dl << 24) | s;
    }
  }
}

// ---------------------------------------------------------------------------
// Per-window counting sort (in LDS, in-place in ebuf) -> CSR order.
// ---------------------------------------------------------------------------
__global__ __launch_bounds__(256) void win_sort(unsigned* __restrict__ ebuf,
                                                const unsigned* __restrict__ bbase,
                                                unsigned* __restrict__ rowptr,
                                                unsigned* __restrict__ deg) {
  __shared__ unsigned earr[WCAP];
  __shared__ unsigned sorted[WCAP];
  __shared__ unsigned hist[WN], pre[WN + 1], cur[WN];
  const int t = threadIdx.x, w = blockIdx.x;
  const int lo = w * WN;
  const unsigned beg = bbase[w], end = bbase[w + 1];
  const int n = (int)(end - beg);
  for (int i = t; i < WN; i += 256) hist[i] = 0;
  __syncthreads();
  for (int i = t; i < n; i += 256) {
    const unsigned p = ebuf[beg + i];
    earr[i] = p;
    atomicAdd(&hist[p >> 24], 1u);
  }
  __syncthreads();
  if (t == 0) {
    unsigned run = 0;
    for (int i = 0; i < WN; ++i) {
      pre[i] = run;
      run += hist[i];
    }
    pre[WN] = run;
  }
  __syncthreads();
  for (int dl = t; dl < WN; dl += 256) {
    const int node = lo + dl;
    if (node <= N_NODES) rowptr[node] = beg + pre[dl];
    if (node < N_NODES) deg[node] = hist[dl];
    cur[dl] = pre[dl];
  }
  __syncthreads();
  for (int i = t; i < n; i += 256) {
    const unsigned p = earr[i];
    const unsigned pos = atomicAdd(&cur[p >> 24], 1u);
    sorted[pos] = p;
  }
  __syncthreads();
  for (int i = t; i < n; i += 256) ebuf[beg + i] = sorted[i];
}

// ---------------------------------------------------------------------------
// Gather-aggregate (mean) over bf16 rows, F=64: 16 lanes/row (ushort4=8B),
// 4 rows in flight, 2-deep unrolled. Output bf16 (aggx).
// ---------------------------------------------------------------------------
__global__ __launch_bounds__(256) void gather64_bf16(
    const ushort4* __restrict__ Xb, const unsigned* __restrict__ rowptr,
    const unsigned* __restrict__ csr, ushort4* __restrict__ aggxb) {
  const int node = (int)((blockIdx.x * 256 + threadIdx.x) >> 6);
  const int lane = threadIdx.x & 63;
  if (node >= N_NODES) return;
  const int g = lane >> 4, q = lane & 15;  // G=16, NG=4
  const unsigned beg = rowptr[node], end = rowptr[node + 1];
  const float inv = (end > beg) ? 1.0f / (float)(end - beg) : 0.0f;

  float ax = 0, ay = 0, az = 0, aw = 0, bx = 0, by = 0, bz = 0, bw = 0;
  unsigned e = beg + g;
  for (; e + 4 < end; e += 8) {
    const ushort4 u0 = Xb[(size_t)(csr[e] & 0xFFFFFFu) * 16 + q];
    const ushort4 u1 = Xb[(size_t)(csr[e + 4] & 0xFFFFFFu) * 16 + q];
    ax += bf2f(u0.x); ay += bf2f(u0.y); az += bf2f(u0.z); aw += bf2f(u0.w);
    bx += bf2f(u1.x); by += bf2f(u1.y); bz += bf2f(u1.z); bw += bf2f(u1.w);
  }
  if (e < end) {
    const ushort4 u = Xb[(size_t)(csr[e] & 0xFFFFFFu) * 16 + q];
    ax += bf2f(u.x); ay += bf2f(u.y); az += bf2f(u.z); aw += bf2f(u.w);
  }
  float sx = ax + bx, sy = ay + by, sz = az + bz, sw = aw + bw;
#pragma unroll
  for (int m = 16; m < 64; m <<= 1) {
    sx += __shfl_xor(sx, m, 64);
    sy += __shfl_xor(sy, m, 64);
    sz += __shfl_xor(sz, m, 64);
    sw += __shfl_xor(sw, m, 64);
  }
  if (g == 0) {
    ushort4 o;
    o.x = f2bf(sx * inv); o.y = f2bf(sy * inv);
    o.z = f2bf(sz * inv); o.w = f2bf(sw * inv);
    aggxb[(size_t)node * 16 + q] = o;
  }
}

// ---------------------------------------------------------------------------
// Gather-aggregate (mean) over bf16 rows, F=32: 8 lanes/row, 8 rows in
// flight, 2-deep. out = mean + hr1 (f32).
// ---------------------------------------------------------------------------
__global__ __launch_bounds__(256) void gather32_bf16(
    const ushort4* __restrict__ H1b, const unsigned* __restrict__ rowptr,
    const unsigned* __restrict__ csr, const float4* __restrict__ HR1,
    float4* __restrict__ outp) {
  const int node = (int)((blockIdx.x * 256 + threadIdx.x) >> 6);
  const int lane = threadIdx.x & 63;
  if (node >= N_NODES) return;
  const int g = lane >> 3, q = lane & 7;  // G=8, NG=8
  const unsigned beg = rowptr[node], end = rowptr[node + 1];
  const float inv = (end > beg) ? 1.0f / (float)(end - beg) : 0.0f;

  float ax = 0, ay = 0, az = 0, aw = 0, bx = 0, by = 0, bz = 0, bw = 0;
  unsigned e = beg + g;
  for (; e + 8 < end; e += 16) {
    const ushort4 u0 = H1b[(size_t)(csr[e] & 0xFFFFFFu) * 8 + q];
    const ushort4 u1 = H1b[(size_t)(csr[e + 8] & 0xFFFFFFu) * 8 + q];
    ax += bf2f(u0.x); ay += bf2f(u0.y); az += bf2f(u0.z); aw += bf2f(u0.w);
    bx += bf2f(u1.x); by += bf2f(u1.y); bz += bf2f(u1.z); bw += bf2f(u1.w);
  }
  if (e < end) {
    const ushort4 u = H1b[(size_t)(csr[e] & 0xFFFFFFu) * 8 + q];
    ax += bf2f(u.x); ay += bf2f(u.y); az += bf2f(u.z); aw += bf2f(u.w);
  }
  float sx = ax + bx, sy = ay + by, sz = az + bz, sw = aw + bw;
#pragma unroll
  for (int m = 8; m < 64; m <<= 1) {
    sx += __shfl_xor(sx, m, 64);
    sy += __shfl_xor(sy, m, 64);
    sz += __shfl_xor(sz, m, 64);
    sw += __shfl_xor(sw, m, 64);
  }
  if (g == 0) {
    const float4 b = HR1[(size_t)node * 8 + q];
    float4 r;
    r.x = sx * inv + b.x;
    r.y = sy * inv + b.y;
    r.z = sz * inv + b.z;
    r.w = sw * inv + b.w;
    outp[(size_t)node * 8 + q] = r;
  }
}

extern "C" void kernel_launch(void* const* d_in, const int* in_sizes, int n_in,
                              void* d_out, int out_size, void* d_ws,
                              size_t ws_size, hipStream_t stream) {
  const float* x = (const float*)d_in[0];
  const int* ei = (const int*)d_in[1];
  const float* Wl0 = (const float*)d_in[2];
  const float* bl0 = (const float*)d_in[3];
  const float* Wr0 = (const float*)d_in[4];
  const float* Wl1 = (const float*)d_in[5];
  const float* bl1 = (const float*)d_in[6];
  const float* Wr1 = (const float*)d_in[7];
  float* out = (float*)d_out;

  const int N = N_NODES;

  // Workspace (16B-aligned segments):
  //   xb    : N*64 bf16 (12.8MB)
  //   aggxb : N*64 bf16 (12.8MB)
  //   h1b   : N*32 bf16 ( 6.4MB)
  //   Wb    : 12288 bf16
  //   hr1   : N*32 f32  (12.8MB)
  //   deg[N], bcnt[1024], bbase[1025], bcursor[1024], rowptr[N+1], ebuf[E]
  unsigned short* xb = (unsigned short*)d_ws;
  unsigned short* aggxb = xb + (size_t)N * 64;
  unsigned short* h1b = aggxb + (size_t)N * 64;
  unsigned short* Wb = h1b + (size_t)N * 32;
  float* hr1 = (float*)(Wb + 12288);
  unsigned* deg = (unsigned*)(hr1 + (size_t)N * 32);
  unsigned* bcnt = deg + N;
  unsigned* bbase = bcnt + NWIN;
  unsigned* bcursor = bbase + (NWIN + 1);
  unsigned* rowptr = bcursor + NWIN;
  unsigned* ebuf = rowptr + (N + 1);

  hipMemsetAsync(bcnt, 0, NWIN * sizeof(unsigned), stream);

  const dim3 blk(256);

  // ---- bf16 conversion of x and weights ----
  conv_bf16<<<(N * 16 + 3072 + 255) / 256, blk, 0, stream>>>(
      (const float4*)x, (const float4*)Wr0, (const float4*)Wl0,
      (const float4*)Wl1, (const float4*)Wr1, (ushort4*)xb, (ushort4*)Wb);

  // ---- edge bucketing + per-window counting sort -> CSR (both layers) ----
  bucket_count<<<CB, blk, 0, stream>>>(ei, bcnt);
  bucket_scan<<<1, NWIN, 0, stream>>>(bcnt, bbase, bcursor);
  bucket_fill<<<FB, blk, 0, stream>>>(ei, bcursor, ebuf);
  win_sort<<<NWIN, blk, 0, stream>>>(ebuf, bbase, rowptr, deg);

  // ---- layer-0 aggregation: aggx = mean(x[src]) (bf16 in/out) ----
  gather64_bf16<<<(N * 64 + 255) / 256, blk, 0, stream>>>(
      (const ushort4*)xb, rowptr, ebuf, (ushort4*)aggxb);

  // ---- fused GEMMs on matrix cores: h in LDS; emits h1 (bf16), hr1 (f32) ----
  gemm01_mfma<<<NTILES, blk, 0, stream>>>(xb, aggxb, Wb, bl0, deg, bl1, h1b,
                                          hr1);

  // ---- layer-1 aggregation + combine: out = mean(h1[src]) + hr1 ----
  gather32_bf16<<<(N * 64 + 255) / 256, blk, 0, stream>>>(
      (const ushort4*)h1b, rowptr, ebuf, (const float4*)hr1, (float4*)out);
}

// Round 11
// 182.154 us; speedup vs baseline: 1.4689x; 1.0569x over previous
//
#include <hip/hip_runtime.h>

#define N_NODES 100000
#define N_EDGES 1600000
#define NWIN 1024
#define WN 98                           // nodes per window; 1024*98 >= N
#define WCAP 4096                       // max edges per window (mean 1562)
#define CB ((N_EDGES + 4095) / 4096)    // 391 count blocks
#define FB ((N_EDGES + 4095) / 4096)    // 391 fill blocks (4096 edges each)
#define NTILES ((N_NODES + 63) / 64)    // 1563 row tiles of 64

typedef __attribute__((ext_vector_type(8))) short bf16x8;
typedef __attribute__((ext_vector_type(4))) float f32x4;

__device__ __forceinline__ unsigned short f2bf(float f) {
  unsigned u = __builtin_bit_cast(unsigned, f);
  u += 0x7FFFu + ((u >> 16) & 1u);  // RNE
  return (unsigned short)(u >> 16);
}
__device__ __forceinline__ float bf2f(unsigned short s) {
  return __builtin_bit_cast(float, (unsigned)s << 16);
}

// ---------------------------------------------------------------------------
// Convert x and the four W matrices to bf16 (one pass).
// Wb layout (ushort): Wr0b @0 (4096), Wl0b @4096, Wl1b @8192, Wr1b @10240.
// ---------------------------------------------------------------------------
__global__ __launch_bounds__(256) void conv_bf16(
    const float4* __restrict__ X4, const float4* __restrict__ Wr0,
    const float4* __restrict__ Wl0, const float4* __restrict__ Wl1,
    const float4* __restrict__ Wr1, ushort4* __restrict__ Xb,
    ushort4* __restrict__ Wb) {
  const int i = blockIdx.x * 256 + threadIdx.x;
  float4 v;
  ushort4* dst;
  if (i < N_NODES * 16) {
    v = X4[i];
    dst = &Xb[i];
  } else {
    const int j = i - N_NODES * 16;
    if (j < 1024) v = Wr0[j];
    else if (j < 2048) v = Wl0[j - 1024];
    else if (j < 2560) v = Wl1[j - 2048];
    else if (j < 3072) v = Wr1[j - 2560];
    else return;
    dst = &Wb[j];
  }
  ushort4 o;
  o.x = f2bf(v.x); o.y = f2bf(v.y); o.z = f2bf(v.z); o.w = f2bf(v.w);
  *dst = o;
}

// ---------------------------------------------------------------------------
// Fused GEMM0+GEMM1 on matrix cores (mfma_f32_16x16x32_bf16).
// ---------------------------------------------------------------------------
__global__ __launch_bounds__(256) void gemm01_mfma(
    const unsigned short* __restrict__ Xb,
    const unsigned short* __restrict__ AGGb,
    const unsigned short* __restrict__ Wb, const float* __restrict__ bl0,
    const unsigned* __restrict__ deg, const float* __restrict__ bl1,
    unsigned short* __restrict__ H1b, float* __restrict__ HR1) {
  __shared__ unsigned short sH[64 * 72];  // +8 bf16 pad: 2-way banks on read
  const int t = threadIdx.x;
  const int lane = t & 63;
  const int w = t >> 6;
  const int rbase = blockIdx.x * 64;
  const int lr = lane & 15;   // A row / B col / D col selector
  const int kg = lane >> 4;   // k-group
  const int row16 = w * 16 + lr;
  const int grow_a = rbase + row16;
  const size_t arow = (size_t)(grow_a < N_NODES ? grow_a : N_NODES - 1);

  const unsigned short* Wr0b = Wb;
  const unsigned short* Wl0b = Wb + 4096;
  const unsigned short* Wl1b = Wb + 8192;
  const unsigned short* Wr1b = Wb + 10240;

  f32x4 acc[4] = {{0, 0, 0, 0}, {0, 0, 0, 0}, {0, 0, 0, 0}, {0, 0, 0, 0}};

  // ---- phase 1: X.Wr0^T + AGG.Wl0^T ----
  {
    const bf16x8 ax0 = *(const bf16x8*)&Xb[arow * 64 + kg * 8];
    const bf16x8 ax1 = *(const bf16x8*)&Xb[arow * 64 + 32 + kg * 8];
    const bf16x8 ag0 = *(const bf16x8*)&AGGb[arow * 64 + kg * 8];
    const bf16x8 ag1 = *(const bf16x8*)&AGGb[arow * 64 + 32 + kg * 8];
#pragma unroll
    for (int cn = 0; cn < 4; ++cn) {
      const int wr = cn * 16 + lr;
      const bf16x8 br0 = *(const bf16x8*)&Wr0b[wr * 64 + kg * 8];
      const bf16x8 br1 = *(const bf16x8*)&Wr0b[wr * 64 + 32 + kg * 8];
      const bf16x8 bl0f = *(const bf16x8*)&Wl0b[wr * 64 + kg * 8];
      const bf16x8 bl1f = *(const bf16x8*)&Wl0b[wr * 64 + 32 + kg * 8];
      acc[cn] = __builtin_amdgcn_mfma_f32_16x16x32_bf16(ax0, br0, acc[cn], 0, 0, 0);
      acc[cn] = __builtin_amdgcn_mfma_f32_16x16x32_bf16(ax1, br1, acc[cn], 0, 0, 0);
      acc[cn] = __builtin_amdgcn_mfma_f32_16x16x32_bf16(ag0, bl0f, acc[cn], 0, 0, 0);
      acc[cn] = __builtin_amdgcn_mfma_f32_16x16x32_bf16(ag1, bl1f, acc[cn], 0, 0, 0);
    }
  }

  // ---- epilogue 0: h = relu(acc + bl0*(deg>0)) -> sH (bf16, LDS only) ----
  const int crow0 = w * 16 + (lane >> 4) * 4;
  float gate[4];
#pragma unroll
  for (int r = 0; r < 4; ++r) {
    const int grow = rbase + crow0 + r;
    gate[r] = (deg[grow < N_NODES ? grow : N_NODES - 1] > 0) ? 1.0f : 0.0f;
  }
#pragma unroll
  for (int cn = 0; cn < 4; ++cn) {
    const int col = cn * 16 + lr;
    const float bias = bl0[col];
#pragma unroll
    for (int r = 0; r < 4; ++r) {
      const float h = fmaxf(fmaf(bias, gate[r], acc[cn][r]), 0.0f);
      sH[(crow0 + r) * 72 + col] = f2bf(h);
    }
  }
  __syncthreads();

  // ---- phase 2: h.{Wl1|Wr1}^T ----
  f32x4 acc2[4] = {{0, 0, 0, 0}, {0, 0, 0, 0}, {0, 0, 0, 0}, {0, 0, 0, 0}};
  {
    const bf16x8 ah0 = *(const bf16x8*)&sH[row16 * 72 + kg * 8];
    const bf16x8 ah1 = *(const bf16x8*)&sH[row16 * 72 + 32 + kg * 8];
#pragma unroll
    for (int cn = 0; cn < 4; ++cn) {
      const int col = cn * 16 + lr;
      const unsigned short* Wp =
          (cn < 2) ? &Wl1b[col * 64] : &Wr1b[(col - 32) * 64];
      const bf16x8 b0 = *(const bf16x8*)&Wp[kg * 8];
      const bf16x8 b1 = *(const bf16x8*)&Wp[32 + kg * 8];
      acc2[cn] = __builtin_amdgcn_mfma_f32_16x16x32_bf16(ah0, b0, acc2[cn], 0, 0, 0);
      acc2[cn] = __builtin_amdgcn_mfma_f32_16x16x32_bf16(ah1, b1, acc2[cn], 0, 0, 0);
    }
  }

  // ---- epilogue 1: h1 (bf16, +bl1) and hr1 (f32) ----
#pragma unroll
  for (int cn = 0; cn < 4; ++cn) {
    const int col = cn * 16 + lr;
    const float bias = (cn < 2) ? bl1[col] : 0.0f;
#pragma unroll
    for (int r = 0; r < 4; ++r) {
      const int grow = rbase + crow0 + r;
      if (grow < N_NODES) {
        if (cn < 2)
          H1b[(size_t)grow * 32 + col] = f2bf(acc2[cn][r] + bias);
        else
          HR1[(size_t)grow * 32 + (col - 32)] = acc2[cn][r];
      }
    }
  }
}

// ---------------------------------------------------------------------------
// Edge bucketing by dst window (1024 windows of 98 nodes).
// ---------------------------------------------------------------------------
__global__ __launch_bounds__(256) void bucket_count(const int* __restrict__ ei,
                                                    unsigned* __restrict__ bcnt) {
  __shared__ unsigned h[NWIN];
  const int t = threadIdx.x;
  for (int i = t; i < NWIN; i += 256) h[i] = 0;
  __syncthreads();
  const long long base = (long long)blockIdx.x * 4096;
#pragma unroll
  for (int i = 0; i < 16; ++i) {
    const long long e = base + i * 256 + t;
    if (e < N_EDGES) {
      const unsigned d = (unsigned)ei[N_EDGES + e];
      atomicAdd(&h[d / WN], 1u);
    }
  }
  __syncthreads();
  for (int i = t; i < NWIN; i += 256) {
    const unsigned c = h[i];
    if (c) atomicAdd(&bcnt[i], c);
  }
}

__global__ __launch_bounds__(1024) void bucket_scan(
    const unsigned* __restrict__ bcnt, unsigned* __restrict__ bbase,
    unsigned* __restrict__ bcursor) {
  __shared__ unsigned s[NWIN];
  const int t = threadIdx.x;
  const unsigned v = bcnt[t];
  s[t] = v;
  __syncthreads();
  for (int off = 1; off < NWIN; off <<= 1) {
    const unsigned u = (t >= off) ? s[t - off] : 0u;
    __syncthreads();
    s[t] += u;
    __syncthreads();
  }
  const unsigned ex = s[t] - v;
  bbase[t] = ex;
  bcursor[t] = ex;
  if (t == NWIN - 1) bbase[NWIN] = s[NWIN - 1];
}

// 4096 edges/block (391 blocks -> full-chip occupancy): LDS histogram ->
// bulk cursor reservation -> packed (dl<<24|src) writes in ~4-entry chunks.
__global__ __launch_bounds__(256) void bucket_fill(const int* __restrict__ ei,
                                                   unsigned* __restrict__ bcursor,
                                                   unsigned* __restrict__ ebuf) {
  __shared__ unsigned lcnt[NWIN], gbase[NWIN];
  const int t = threadIdx.x;
  for (int i = t; i < NWIN; i += 256) lcnt[i] = 0;
  __syncthreads();
  const long long base = (long long)blockIdx.x * 4096;
#pragma unroll 4
  for (int i = 0; i < 16; ++i) {
    const long long e = base + i * 256 + t;
    if (e < N_EDGES) {
      const unsigned d = (unsigned)ei[N_EDGES + e];
      atomicAdd(&lcnt[d / WN], 1u);
    }
  }
  __syncthreads();
  for (int i = t; i < NWIN; i += 256) {
    const unsigned c = lcnt[i];
    gbase[i] = c ? atomicAdd(&bcursor[i], c) : 0u;
    lcnt[i] = 0;  // reused as local cursor
  }
  __syncthreads();
#pragma unroll 4
  for (int i = 0; i < 16; ++i) {
    const long long e = base + i * 256 + t;
    if (e < N_EDGES) {
      const unsigned s = (unsigned)ei[e];
      const unsigned d = (unsigned)ei[N_EDGES + e];
      const unsigned b = d / WN, dl = d - b * WN;
      const unsigned off = atomicAdd(&lcnt[b], 1u);
      ebuf[gbase[b] + off] = (dl << 24) | s;
    }
  }
}

// ---------------------------------------------------------------------------
// Per-window counting sort (in LDS, in-place in ebuf) -> CSR order.
// ---------------------------------------------------------------------------
__global__ __launch_bounds__(256) void win_sort(unsigned* __restrict__ ebuf,
                                                const unsigned* __restrict__ bbase,
                                                unsigned* __restrict__ rowptr,
                                                unsigned* __restrict__ deg) {
  __shared__ unsigned earr[WCAP];
  __shared__ unsigned sorted[WCAP];
  __shared__ unsigned hist[WN], pre[WN + 1], cur[WN];
  const int t = threadIdx.x, w = blockIdx.x;
  const int lo = w * WN;
  const unsigned beg = bbase[w], end = bbase[w + 1];
  const int n = (int)(end - beg);
  for (int i = t; i < WN; i += 256) hist[i] = 0;
  __syncthreads();
  for (int i = t; i < n; i += 256) {
    const unsigned p = ebuf[beg + i];
    earr[i] = p;
    atomicAdd(&hist[p >> 24], 1u);
  }
  __syncthreads();
  if (t == 0) {
    unsigned run = 0;
    for (int i = 0; i < WN; ++i) {
      pre[i] = run;
      run += hist[i];
    }
    pre[WN] = run;
  }
  __syncthreads();
  for (int dl = t; dl < WN; dl += 256) {
    const int node = lo + dl;
    if (node <= N_NODES) rowptr[node] = beg + pre[dl];
    if (node < N_NODES) deg[node] = hist[dl];
    cur[dl] = pre[dl];
  }
  __syncthreads();
  for (int i = t; i < n; i += 256) {
    const unsigned p = earr[i];
    const unsigned pos = atomicAdd(&cur[p >> 24], 1u);
    sorted[pos] = p;
  }
  __syncthreads();
  for (int i = t; i < n; i += 256) ebuf[beg + i] = sorted[i];
}

// ---------------------------------------------------------------------------
// Gather-aggregate (mean) over bf16 rows, F=64: 16 lanes/row (ushort4=8B),
// 4 rows in flight, 2-deep unrolled. Output bf16 (aggx).
// ---------------------------------------------------------------------------
__global__ __launch_bounds__(256) void gather64_bf16(
    const ushort4* __restrict__ Xb, const unsigned* __restrict__ rowptr,
    const unsigned* __restrict__ csr, ushort4* __restrict__ aggxb) {
  const int node = (int)((blockIdx.x * 256 + threadIdx.x) >> 6);
  const int lane = threadIdx.x & 63;
  if (node >= N_NODES) return;
  const int g = lane >> 4, q = lane & 15;  // G=16, NG=4
  const unsigned beg = rowptr[node], end = rowptr[node + 1];
  const float inv = (end > beg) ? 1.0f / (float)(end - beg) : 0.0f;

  float ax = 0, ay = 0, az = 0, aw = 0, bx = 0, by = 0, bz = 0, bw = 0;
  unsigned e = beg + g;
  for (; e + 4 < end; e += 8) {
    const ushort4 u0 = Xb[(size_t)(csr[e] & 0xFFFFFFu) * 16 + q];
    const ushort4 u1 = Xb[(size_t)(csr[e + 4] & 0xFFFFFFu) * 16 + q];
    ax += bf2f(u0.x); ay += bf2f(u0.y); az += bf2f(u0.z); aw += bf2f(u0.w);
    bx += bf2f(u1.x); by += bf2f(u1.y); bz += bf2f(u1.z); bw += bf2f(u1.w);
  }
  if (e < end) {
    const ushort4 u = Xb[(size_t)(csr[e] & 0xFFFFFFu) * 16 + q];
    ax += bf2f(u.x); ay += bf2f(u.y); az += bf2f(u.z); aw += bf2f(u.w);
  }
  float sx = ax + bx, sy = ay + by, sz = az + bz, sw = aw + bw;
#pragma unroll
  for (int m = 16; m < 64; m <<= 1) {
    sx += __shfl_xor(sx, m, 64);
    sy += __shfl_xor(sy, m, 64);
    sz += __shfl_xor(sz, m, 64);
    sw += __shfl_xor(sw, m, 64);
  }
  if (g == 0) {
    ushort4 o;
    o.x = f2bf(sx * inv); o.y = f2bf(sy * inv);
    o.z = f2bf(sz * inv); o.w = f2bf(sw * inv);
    aggxb[(size_t)node * 16 + q] = o;
  }
}

// ---------------------------------------------------------------------------
// Gather-aggregate (mean) over bf16 rows, F=32: 8 lanes/row, 8 rows in
// flight, 2-deep. out = mean + hr1 (f32).
// ---------------------------------------------------------------------------
__global__ __launch_bounds__(256) void gather32_bf16(
    const ushort4* __restrict__ H1b, const unsigned* __restrict__ rowptr,
    const unsigned* __restrict__ csr, const float4* __restrict__ HR1,
    float4* __restrict__ outp) {
  const int node = (int)((blockIdx.x * 256 + threadIdx.x) >> 6);
  const int lane = threadIdx.x & 63;
  if (node >= N_NODES) return;
  const int g = lane >> 3, q = lane & 7;  // G=8, NG=8
  const unsigned beg = rowptr[node], end = rowptr[node + 1];
  const float inv = (end > beg) ? 1.0f / (float)(end - beg) : 0.0f;

  float ax = 0, ay = 0, az = 0, aw = 0, bx = 0, by = 0, bz = 0, bw = 0;
  unsigned e = beg + g;
  for (; e + 8 < end; e += 16) {
    const ushort4 u0 = H1b[(size_t)(csr[e] & 0xFFFFFFu) * 8 + q];
    const ushort4 u1 = H1b[(size_t)(csr[e + 8] & 0xFFFFFFu) * 8 + q];
    ax += bf2f(u0.x); ay += bf2f(u0.y); az += bf2f(u0.z); aw += bf2f(u0.w);
    bx += bf2f(u1.x); by += bf2f(u1.y); bz += bf2f(u1.z); bw += bf2f(u1.w);
  }
  if (e < end) {
    const ushort4 u = H1b[(size_t)(csr[e] & 0xFFFFFFu) * 8 + q];
    ax += bf2f(u.x); ay += bf2f(u.y); az += bf2f(u.z); aw += bf2f(u.w);
  }
  float sx = ax + bx, sy = ay + by, sz = az + bz, sw = aw + bw;
#pragma unroll
  for (int m = 8; m < 64; m <<= 1) {
    sx += __shfl_xor(sx, m, 64);
    sy += __shfl_xor(sy, m, 64);
    sz += __shfl_xor(sz, m, 64);
    sw += __shfl_xor(sw, m, 64);
  }
  if (g == 0) {
    const float4 b = HR1[(size_t)node * 8 + q];
    float4 r;
    r.x = sx * inv + b.x;
    r.y = sy * inv + b.y;
    r.z = sz * inv + b.z;
    r.w = sw * inv + b.w;
    outp[(size_t)node * 8 + q] = r;
  }
}

extern "C" void kernel_launch(void* const* d_in, const int* in_sizes, int n_in,
                              void* d_out, int out_size, void* d_ws,
                              size_t ws_size, hipStream_t stream) {
  const float* x = (const float*)d_in[0];
  const int* ei = (const int*)d_in[1];
  const float* Wl0 = (const float*)d_in[2];
  const float* bl0 = (const float*)d_in[3];
  const float* Wr0 = (const float*)d_in[4];
  const float* Wl1 = (const float*)d_in[5];
  const float* bl1 = (const float*)d_in[6];
  const float* Wr1 = (const float*)d_in[7];
  float* out = (float*)d_out;

  const int N = N_NODES;

  // Workspace (16B-aligned segments):
  //   xb    : N*64 bf16 (12.8MB)
  //   aggxb : N*64 bf16 (12.8MB)
  //   h1b   : N*32 bf16 ( 6.4MB)
  //   Wb    : 12288 bf16
  //   hr1   : N*32 f32  (12.8MB)
  //   deg[N], bcnt[1024], bbase[1025], bcursor[1024], rowptr[N+1], ebuf[E]
  unsigned short* xb = (unsigned short*)d_ws;
  unsigned short* aggxb = xb + (size_t)N * 64;
  unsigned short* h1b = aggxb + (size_t)N * 64;
  unsigned short* Wb = h1b + (size_t)N * 32;
  float* hr1 = (float*)(Wb + 12288);
  unsigned* deg = (unsigned*)(hr1 + (size_t)N * 32);
  unsigned* bcnt = deg + N;
  unsigned* bbase = bcnt + NWIN;
  unsigned* bcursor = bbase + (NWIN + 1);
  unsigned* rowptr = bcursor + NWIN;
  unsigned* ebuf = rowptr + (N + 1);

  hipMemsetAsync(bcnt, 0, NWIN * sizeof(unsigned), stream);

  const dim3 blk(256);

  // ---- bf16 conversion of x and weights ----
  conv_bf16<<<(N * 16 + 3072 + 255) / 256, blk, 0, stream>>>(
      (const float4*)x, (const float4*)Wr0, (const float4*)Wl0,
      (const float4*)Wl1, (const float4*)Wr1, (ushort4*)xb, (ushort4*)Wb);

  // ---- edge bucketing + per-window counting sort -> CSR (both layers) ----
  bucket_count<<<CB, blk, 0, stream>>>(ei, bcnt);
  bucket_scan<<<1, NWIN, 0, stream>>>(bcnt, bbase, bcursor);
  bucket_fill<<<FB, blk, 0, stream>>>(ei, bcursor, ebuf);
  win_sort<<<NWIN, blk, 0, stream>>>(ebuf, bbase, rowptr, deg);

  // ---- layer-0 aggregation: aggx = mean(x[src]) (bf16 in/out) ----
  gather64_bf16<<<(N * 64 + 255) / 256, blk, 0, stream>>>(
      (const ushort4*)xb, rowptr, ebuf, (ushort4*)aggxb);

  // ---- fused GEMMs on matrix cores: h in LDS; emits h1 (bf16), hr1 (f32) ----
  gemm01_mfma<<<NTILES, blk, 0, stream>>>(xb, aggxb, Wb, bl0, deg, bl1, h1b,
                                          hr1);

  // ---- layer-1 aggregation + combine: out = mean(h1[src]) + hr1 ----
  gather32_bf16<<<(N * 64 + 255) / 256, blk, 0, stream>>>(
      (const ushort4*)h1b, rowptr, ebuf, (const float4*)hr1, (float4*)out);
}